// Round 1
// baseline (389.395 us; speedup 1.0000x reference)
//
#include <hip/hip_runtime.h>
#include <hip/hip_bf16.h>
#include <math.h>

#define B_SZ   16
#define N_ATOM 286
#define K_TAB  8192
#define HIDW   150
#define FF_DIM 512

__device__ __forceinline__ float softplus_f(float x) {
  return fmaxf(x, 0.0f) + log1pf(expf(-fabsf(x)));
}
// torch Softplus(beta=5): softplus(5x)/5
__device__ __forceinline__ float sp5_f(float x) {
  float t = 5.0f * x;
  return (fmaxf(t, 0.0f) + log1pf(expf(-fabsf(t)))) * 0.2f;
}

// feats0[t][:] = emb[Z[t]][:]
__global__ __launch_bounds__(256) void gather_kernel(
    const int* __restrict__ Z, const float* __restrict__ emb,
    float* __restrict__ feats0) {
  int t = blockIdx.x * 256 + threadIdx.x;
  if (t < B_SZ * N_ATOM) {
    int zi = Z[t];
    float4 e = *(const float4*)(emb + (size_t)zi * 4);
    *(float4*)(feats0 + (size_t)t * 4) = e;
  }
}

// Tabulate the radial MLP R(r) (16 outputs) at r = 3*e/K_TAB, e = 0..K_TAB.
// One wave handles 4 consecutive entries; hidden activations ping-pong in LDS.
__global__ __launch_bounds__(256) void table_kernel(
    const float* __restrict__ w0, const float* __restrict__ b0,
    const float* __restrict__ w1, const float* __restrict__ b1,
    const float* __restrict__ w2, const float* __restrict__ b2,
    const float* __restrict__ w3, const float* __restrict__ b3,
    float* __restrict__ table) {
  __shared__ float hA[4][4][152];  // [wave][entry][neuron]
  __shared__ float hB[4][4][152];
  const int wave = threadIdx.x >> 6;
  const int lane = threadIdx.x & 63;
  const int wglobal = blockIdx.x * 4 + wave;
  const int e0 = wglobal * 4;

  // cosine basis (3 values) per entry — all lanes compute redundantly (cheap)
  float x[4][3];
  #pragma unroll
  for (int e = 0; e < 4; ++e) {
    int ei = e0 + e; if (ei > K_TAB) ei = K_TAB;   // clamp for padding waves
    float r = 3.0f * (float)ei / (float)K_TAB;
    #pragma unroll
    for (int k = 0; k < 3; ++k) {
      float d = (r - 1.5f * (float)k) * (1.0f / 1.5f);
      float c = cosf(1.57079632679489662f * d);
      x[e][k] = (fabsf(d) < 1.0f) ? c * c : 0.0f;
    }
  }

  // layer 0: 3 -> 150
  #pragma unroll
  for (int rep = 0; rep < 3; ++rep) {
    int o = lane + rep * 64;
    if (o < HIDW) {
      float wv0 = w0[o], wv1 = w0[HIDW + o], wv2 = w0[2 * HIDW + o];
      float bb = b0[o];
      #pragma unroll
      for (int e = 0; e < 4; ++e)
        hA[wave][e][o] = sp5_f(bb + x[e][0] * wv0 + x[e][1] * wv1 + x[e][2] * wv2);
    }
  }
  __syncthreads();

  // layers 1,2: 150 -> 150   (layer 0 reads hA writes hB; layer 1 reads hB writes hA)
  float* bufA = &hA[wave][0][0];
  float* bufB = &hB[wave][0][0];
  #pragma unroll
  for (int layer = 0; layer < 2; ++layer) {
    const float* W  = layer ? w2 : w1;
    const float* Bb = layer ? b2 : b1;
    const float* src = layer ? bufB : bufA;
    float*       dst = layer ? bufA : bufB;
    float acc[3][4];
    #pragma unroll
    for (int rep = 0; rep < 3; ++rep) {
      int o = lane + rep * 64;
      float bb = (o < HIDW) ? Bb[o] : 0.0f;
      #pragma unroll
      for (int e = 0; e < 4; ++e) acc[rep][e] = bb;
    }
    for (int i = 0; i < HIDW; ++i) {
      float h0 = src[0 * 152 + i], h1 = src[1 * 152 + i];
      float h2 = src[2 * 152 + i], h3 = src[3 * 152 + i];
      #pragma unroll
      for (int rep = 0; rep < 3; ++rep) {
        int o = lane + rep * 64;
        if (o < HIDW) {
          float wv = W[i * HIDW + o];            // coalesced across lanes
          acc[rep][0] += h0 * wv; acc[rep][1] += h1 * wv;
          acc[rep][2] += h2 * wv; acc[rep][3] += h3 * wv;
        }
      }
    }
    __syncthreads();
    #pragma unroll
    for (int rep = 0; rep < 3; ++rep) {
      int o = lane + rep * 64;
      if (o < HIDW) {
        #pragma unroll
        for (int e = 0; e < 4; ++e) dst[e * 152 + o] = sp5_f(acc[rep][e]);
      }
    }
    __syncthreads();
  }

  // final layer: 150 -> 16 (no activation). Input is bufA.
  if (lane < 16) {
    float acc[4];
    #pragma unroll
    for (int e = 0; e < 4; ++e) acc[e] = b3[lane];
    for (int i = 0; i < HIDW; ++i) {
      float wv = w3[i * 16 + lane];
      #pragma unroll
      for (int e = 0; e < 4; ++e) acc[e] += bufA[e * 152 + i] * wv;
    }
    #pragma unroll
    for (int e = 0; e < 4; ++e) {
      int ei = e0 + e;
      if (ei <= K_TAB) table[(size_t)ei * 16 + lane] = acc[e];
    }
  }
}

// One wave per output row (z,a): lanes stride neighbors b, lerp R(r) from table,
// 4x4 matvec with feats[z,b,:], wave-reduce, scale by 1/sqrt(nb).
__global__ __launch_bounds__(256) void conv_kernel(
    const float* __restrict__ xyz, const float* __restrict__ feats_in,
    const float* __restrict__ table, float* __restrict__ f_out) {
  const int wave = threadIdx.x >> 6;
  const int lane = threadIdx.x & 63;
  const int row = blockIdx.x * 4 + wave;
  if (row >= B_SZ * N_ATOM) return;
  const int z = row / N_ATOM, a = row % N_ATOM;
  const float* xz = xyz + (size_t)z * N_ATOM * 3;
  const float ax = xz[a * 3 + 0], ay = xz[a * 3 + 1], az = xz[a * 3 + 2];

  float acc[4] = {0.f, 0.f, 0.f, 0.f};
  float cnt = 0.f;
  for (int b = lane; b < N_ATOM; b += 64) {
    float bx = xz[b * 3 + 0], by = xz[b * 3 + 1], bz = xz[b * 3 + 2];
    float dx = ax - bx, dy = ay - by, dz = az - bz;
    float r = sqrtf(dx * dx + dy * dy + dz * dz + 1e-12f);
    if (r < 3.0f) {
      cnt += 1.0f;
      float t = r * ((float)K_TAB / 3.0f);
      int idx = (int)t;
      if (idx > K_TAB - 1) idx = K_TAB - 1;
      float fr = t - (float)idx;
      const float4* T0 = (const float4*)(table + (size_t)idx * 16);
      const float4* T1 = (const float4*)(table + (size_t)idx * 16 + 16);
      float4 fb = *(const float4*)(feats_in + ((size_t)z * N_ATOM + b) * 4);
      #pragma unroll
      for (int i = 0; i < 4; ++i) {
        float4 r0 = T0[i], r1 = T1[i];
        float v0 = r0.x + fr * (r1.x - r0.x);
        float v1 = r0.y + fr * (r1.y - r0.y);
        float v2 = r0.z + fr * (r1.z - r0.z);
        float v3 = r0.w + fr * (r1.w - r0.w);
        acc[i] += v0 * fb.x + v1 * fb.y + v2 * fb.z + v3 * fb.w;
      }
    }
  }
  #pragma unroll
  for (int m = 32; m > 0; m >>= 1) {
    #pragma unroll
    for (int i = 0; i < 4; ++i) acc[i] += __shfl_xor(acc[i], m, 64);
    cnt += __shfl_xor(cnt, m, 64);
  }
  if (lane == 0) {
    float nb = cnt < 1.0f ? 1.0f : cnt;
    float sc = 1.0f / sqrtf(nb);
    float4 o;
    o.x = acc[0] * sc; o.y = acc[1] * sc; o.z = acc[2] * sc; o.w = acc[3] * sc;
    *(float4*)(f_out + (size_t)row * 4) = o;
  }
}

// L2 pool over atoms -> FC(8->512)+softplus -> batchnorm over B -> softplus
// -> FC(512->1) -> sigmoid.   Single block of 512 threads.
__global__ __launch_bounds__(512) void tail_kernel(
    const float* __restrict__ f1, const float* __restrict__ f2,
    const float* __restrict__ fc_w, const float* __restrict__ fc_b,
    const float* __restrict__ bn_g, const float* __restrict__ bn_b,
    const float* __restrict__ out_w, const float* __restrict__ out_b,
    float* __restrict__ out) {
  __shared__ float pooled[16][8];
  __shared__ float part[8][16];
  const int tid = threadIdx.x;

  if (tid < 128) {
    int z = tid >> 3, c = tid & 7;
    const float* src = (c < 4) ? f1 : f2;
    int cc = c & 3;
    float s = 0.f;
    for (int a = 0; a < N_ATOM; ++a) {
      float v = src[((size_t)z * N_ATOM + a) * 4 + cc];
      s += v * v;
    }
    pooled[z][c] = sqrtf(s);
  }
  __syncthreads();

  const int f = tid;
  float hv[16];
  float mean = 0.f;
  #pragma unroll
  for (int z = 0; z < 16; ++z) {
    float a = fc_b[f];
    #pragma unroll
    for (int c = 0; c < 8; ++c) a += pooled[z][c] * fc_w[c * FF_DIM + f];
    hv[z] = softplus_f(a);
    mean += hv[z];
  }
  mean *= (1.0f / 16.0f);
  float var = 0.f;
  #pragma unroll
  for (int z = 0; z < 16; ++z) { float d = hv[z] - mean; var += d * d; }
  var *= (1.0f / 16.0f);
  float istd = 1.0f / sqrtf(var + 1e-5f);
  float g = bn_g[f], bb = bn_b[f], ow = out_w[f];
  float contrib[16];
  #pragma unroll
  for (int z = 0; z < 16; ++z)
    contrib[z] = softplus_f((hv[z] - mean) * istd * g + bb) * ow;

  const int lane = tid & 63, wv = tid >> 6;
  #pragma unroll
  for (int m = 32; m > 0; m >>= 1) {
    #pragma unroll
    for (int z = 0; z < 16; ++z) contrib[z] += __shfl_xor(contrib[z], m, 64);
  }
  if (lane == 0) {
    #pragma unroll
    for (int z = 0; z < 16; ++z) part[wv][z] = contrib[z];
  }
  __syncthreads();
  if (tid < 16) {
    float s = out_b[0];
    #pragma unroll
    for (int w8 = 0; w8 < 8; ++w8) s += part[w8][tid];
    out[tid] = 1.0f / (1.0f + expf(-s));
  }
}

extern "C" void kernel_launch(void* const* d_in, const int* in_sizes, int n_in,
                              void* d_out, int out_size, void* d_ws, size_t ws_size,
                              hipStream_t stream) {
  const float* xyz = (const float*)d_in[0];
  const int*   Z   = (const int*)d_in[1];
  const float* emb = (const float*)d_in[2];
  const float* c0[8]; const float* c1[8];
  for (int i = 0; i < 8; ++i) {
    c0[i] = (const float*)d_in[3 + i];
    c1[i] = (const float*)d_in[11 + i];
  }
  const float* fc_w  = (const float*)d_in[19];
  const float* fc_b  = (const float*)d_in[20];
  const float* bn_g  = (const float*)d_in[21];
  const float* bn_b  = (const float*)d_in[22];
  const float* out_w = (const float*)d_in[23];
  const float* out_b = (const float*)d_in[24];
  float* out = (float*)d_out;

  float* wsf = (float*)d_ws;
  const size_t TAB_ELEMS = (size_t)(K_TAB + 1) * 16;
  float* t0 = wsf;
  float* t1 = t0 + TAB_ELEMS;
  float* feats0 = t1 + TAB_ELEMS;
  float* f1 = feats0 + (size_t)B_SZ * N_ATOM * 4;
  float* f2 = f1 + (size_t)B_SZ * N_ATOM * 4;

  gather_kernel<<<(B_SZ * N_ATOM + 255) / 256, 256, 0, stream>>>(Z, emb, feats0);

  const int waves_t = (K_TAB + 1 + 3) / 4;       // 2049 waves (4 entries each)
  const int blocks_t = (waves_t + 3) / 4;        // 513 blocks of 4 waves
  table_kernel<<<blocks_t, 256, 0, stream>>>(
      c0[0], c0[1], c0[2], c0[3], c0[4], c0[5], c0[6], c0[7], t0);
  table_kernel<<<blocks_t, 256, 0, stream>>>(
      c1[0], c1[1], c1[2], c1[3], c1[4], c1[5], c1[6], c1[7], t1);

  const int conv_blocks = (B_SZ * N_ATOM) / 4;   // 1144, exact
  conv_kernel<<<conv_blocks, 256, 0, stream>>>(xyz, feats0, t0, f1);
  conv_kernel<<<conv_blocks, 256, 0, stream>>>(xyz, f1, t1, f2);

  tail_kernel<<<1, 512, 0, stream>>>(f1, f2, fc_w, fc_b, bn_g, bn_b,
                                     out_w, out_b, out);
}

// Round 2
// 226.988 us; speedup vs baseline: 1.7155x; 1.7155x over previous
//
#include <hip/hip_runtime.h>
#include <hip/hip_bf16.h>
#include <math.h>

#define B_SZ   16
#define N_ATOM 286
#define NT     4096            // table entries, r_e = 3*e/(NT-1)
#define HIDW   150
#define FF_DIM 512
#define E_W    8               // entries per wave
#define BLK_PER_CLOUD ((NT) / (4 * E_W))   // 128

__device__ __forceinline__ float softplus_f(float x) {
  return fmaxf(x, 0.0f) + log1pf(expf(-fabsf(x)));
}
// torch Softplus(beta=5): softplus(5x)/5
__device__ __forceinline__ float sp5_f(float x) {
  float t = 5.0f * x;
  return (fmaxf(t, 0.0f) + log1pf(expf(-fabsf(t)))) * 0.2f;
}

// feats0[t][:] = emb[Z[t]][:]
__global__ __launch_bounds__(256) void gather_kernel(
    const int* __restrict__ Z, const float* __restrict__ emb,
    float* __restrict__ feats0) {
  int t = blockIdx.x * 256 + threadIdx.x;
  if (t < B_SZ * N_ATOM) {
    int zi = Z[t];
    float4 e = *(const float4*)(emb + (size_t)zi * 4);
    *(float4*)(feats0 + (size_t)t * 4) = e;
  }
}

// Tabulate the radial MLP R(r) (16 outputs) at r = 3*e/(NT-1), e=0..NT-1.
// Both clouds in one launch: blockIdx.x < 128 -> cloud0, else cloud1.
// Block = 256 thr = 4 waves; each wave owns E_W=8 entries.
// 150x150 weight matrix staged in LDS (ping-ponged W1 -> W2).
__global__ __launch_bounds__(256) void table_kernel(
    const float* __restrict__ a_w0, const float* __restrict__ a_b0,
    const float* __restrict__ a_w1, const float* __restrict__ a_b1,
    const float* __restrict__ a_w2, const float* __restrict__ a_b2,
    const float* __restrict__ a_w3, const float* __restrict__ a_b3,
    const float* __restrict__ c_w0, const float* __restrict__ c_b0,
    const float* __restrict__ c_w1, const float* __restrict__ c_b1,
    const float* __restrict__ c_w2, const float* __restrict__ c_b2,
    const float* __restrict__ c_w3, const float* __restrict__ c_b3,
    float* __restrict__ tab0, float* __restrict__ tab1) {
  __shared__ float Wlds[150 * 150 + 64];          // 90.25 KB, +pad for lazy lanes
  __shared__ float act[4][2][150 * E_W];          // [wave][pingpong][i*8+e], 38.4 KB

  const int cloud = (blockIdx.x >= BLK_PER_CLOUD) ? 1 : 0;
  const int blk   = blockIdx.x - cloud * BLK_PER_CLOUD;
  const float* w0 = cloud ? c_w0 : a_w0;  const float* b0 = cloud ? c_b0 : a_b0;
  const float* w1 = cloud ? c_w1 : a_w1;  const float* b1 = cloud ? c_b1 : a_b1;
  const float* w2 = cloud ? c_w2 : a_w2;  const float* b2 = cloud ? c_b2 : a_b2;
  const float* w3 = cloud ? c_w3 : a_w3;  const float* b3 = cloud ? c_b3 : a_b3;
  float* table = cloud ? tab1 : tab0;

  const int tid  = threadIdx.x;
  const int wave = tid >> 6;
  const int lane = tid & 63;
  const int base = blk * (4 * E_W) + wave * E_W;  // first entry of this wave

  // ---- stage W1 into LDS (coalesced float4 copy) ----
  {
    const float4* src = (const float4*)w1;
    float4* dst = (float4*)Wlds;
    #pragma unroll
    for (int k = tid; k < (150 * 150) / 4; k += 256) dst[k] = src[k];
  }

  // ---- layer 0: 3 -> 150, write actA ----
  float x[E_W][3];
  #pragma unroll
  for (int e = 0; e < E_W; ++e) {
    float r = 3.0f * (float)(base + e) / (float)(NT - 1);
    #pragma unroll
    for (int k = 0; k < 3; ++k) {
      float d = (r - 1.5f * (float)k) * (1.0f / 1.5f);
      float c = cosf(1.57079632679489662f * d);
      x[e][k] = (fabsf(d) < 1.0f) ? c * c : 0.0f;
    }
  }
  float* actA = &act[wave][0][0];
  float* actB = &act[wave][1][0];
  #pragma unroll
  for (int rep = 0; rep < 3; ++rep) {
    int o = lane + rep * 64;
    if (o < HIDW) {
      float wv0 = w0[o], wv1 = w0[HIDW + o], wv2 = w0[2 * HIDW + o];
      float bb = b0[o];
      float v[E_W];
      #pragma unroll
      for (int e = 0; e < E_W; ++e)
        v[e] = sp5_f(bb + x[e][0] * wv0 + x[e][1] * wv1 + x[e][2] * wv2);
      *(float4*)&actA[o * E_W]     = make_float4(v[0], v[1], v[2], v[3]);
      *(float4*)&actA[o * E_W + 4] = make_float4(v[4], v[5], v[6], v[7]);
    }
  }
  __syncthreads();

  // ---- layer 1: actA x W1(LDS) -> actB ----
  {
    float acc[3][E_W];
    #pragma unroll
    for (int rep = 0; rep < 3; ++rep) {
      int o = lane + rep * 64;
      float bb = (o < HIDW) ? b1[o] : 0.0f;
      #pragma unroll
      for (int e = 0; e < E_W; ++e) acc[rep][e] = bb;
    }
    #pragma unroll 5
    for (int i = 0; i < HIDW; ++i) {
      float4 hlo = *(const float4*)&actA[i * E_W];
      float4 hhi = *(const float4*)&actA[i * E_W + 4];
      #pragma unroll
      for (int rep = 0; rep < 3; ++rep) {
        float wv = Wlds[i * 150 + lane + rep * 64];
        acc[rep][0] += hlo.x * wv; acc[rep][1] += hlo.y * wv;
        acc[rep][2] += hlo.z * wv; acc[rep][3] += hlo.w * wv;
        acc[rep][4] += hhi.x * wv; acc[rep][5] += hhi.y * wv;
        acc[rep][6] += hhi.z * wv; acc[rep][7] += hhi.w * wv;
      }
    }
    __syncthreads();   // all waves done reading W1 (and actA)
    #pragma unroll
    for (int rep = 0; rep < 3; ++rep) {
      int o = lane + rep * 64;
      if (o < HIDW) {
        float v[E_W];
        #pragma unroll
        for (int e = 0; e < E_W; ++e) v[e] = sp5_f(acc[rep][e]);
        *(float4*)&actB[o * E_W]     = make_float4(v[0], v[1], v[2], v[3]);
        *(float4*)&actB[o * E_W + 4] = make_float4(v[4], v[5], v[6], v[7]);
      }
    }
  }

  // ---- stage W2 over W1 ----
  {
    const float4* src = (const float4*)w2;
    float4* dst = (float4*)Wlds;
    #pragma unroll
    for (int k = tid; k < (150 * 150) / 4; k += 256) dst[k] = src[k];
  }
  __syncthreads();

  // ---- layer 2: actB x W2(LDS) -> actA ----
  {
    float acc[3][E_W];
    #pragma unroll
    for (int rep = 0; rep < 3; ++rep) {
      int o = lane + rep * 64;
      float bb = (o < HIDW) ? b2[o] : 0.0f;
      #pragma unroll
      for (int e = 0; e < E_W; ++e) acc[rep][e] = bb;
    }
    #pragma unroll 5
    for (int i = 0; i < HIDW; ++i) {
      float4 hlo = *(const float4*)&actB[i * E_W];
      float4 hhi = *(const float4*)&actB[i * E_W + 4];
      #pragma unroll
      for (int rep = 0; rep < 3; ++rep) {
        float wv = Wlds[i * 150 + lane + rep * 64];
        acc[rep][0] += hlo.x * wv; acc[rep][1] += hlo.y * wv;
        acc[rep][2] += hlo.z * wv; acc[rep][3] += hlo.w * wv;
        acc[rep][4] += hhi.x * wv; acc[rep][5] += hhi.y * wv;
        acc[rep][6] += hhi.z * wv; acc[rep][7] += hhi.w * wv;
      }
    }
    // actA is wave-private; no block barrier needed before overwrite
    #pragma unroll
    for (int rep = 0; rep < 3; ++rep) {
      int o = lane + rep * 64;
      if (o < HIDW) {
        float v[E_W];
        #pragma unroll
        for (int e = 0; e < E_W; ++e) v[e] = sp5_f(acc[rep][e]);
        *(float4*)&actA[o * E_W]     = make_float4(v[0], v[1], v[2], v[3]);
        *(float4*)&actA[o * E_W + 4] = make_float4(v[4], v[5], v[6], v[7]);
      }
    }
  }

  // ---- layer 3: 150 -> 16 (linear). lanes = 16 outputs x 4 entry-groups ----
  {
    const int o   = lane & 15;
    const int grp = lane >> 4;          // each group handles entries 2g, 2g+1
    float acc0 = b3[o], acc1 = b3[o];
    const int e0 = 2 * grp, e1 = 2 * grp + 1;
    for (int i = 0; i < HIDW; ++i) {
      float wv = w3[i * 16 + o];
      acc0 += actA[i * E_W + e0] * wv;
      acc1 += actA[i * E_W + e1] * wv;
    }
    table[(size_t)(base + e0) * 16 + o] = acc0;
    table[(size_t)(base + e1) * 16 + o] = acc1;
  }
}

// One wave per output row (z,a): lanes stride neighbors b, lerp R(r) from table,
// 4x4 matvec with feats[z,b,:], wave-reduce, scale by 1/sqrt(nb).
__global__ __launch_bounds__(256) void conv_kernel(
    const float* __restrict__ xyz, const float* __restrict__ feats_in,
    const float* __restrict__ table, float* __restrict__ f_out) {
  const int wave = threadIdx.x >> 6;
  const int lane = threadIdx.x & 63;
  const int row = blockIdx.x * 4 + wave;
  if (row >= B_SZ * N_ATOM) return;
  const int z = row / N_ATOM, a = row % N_ATOM;
  const float* xz = xyz + (size_t)z * N_ATOM * 3;
  const float ax = xz[a * 3 + 0], ay = xz[a * 3 + 1], az = xz[a * 3 + 2];

  float acc[4] = {0.f, 0.f, 0.f, 0.f};
  float cnt = 0.f;
  for (int b = lane; b < N_ATOM; b += 64) {
    float bx = xz[b * 3 + 0], by = xz[b * 3 + 1], bz = xz[b * 3 + 2];
    float dx = ax - bx, dy = ay - by, dz = az - bz;
    float r = sqrtf(dx * dx + dy * dy + dz * dz + 1e-12f);
    if (r < 3.0f) {
      cnt += 1.0f;
      float t = r * ((float)(NT - 1) / 3.0f);
      int idx = (int)t;
      if (idx > NT - 2) idx = NT - 2;
      float fr = t - (float)idx;
      const float4* T0 = (const float4*)(table + (size_t)idx * 16);
      const float4* T1 = (const float4*)(table + (size_t)idx * 16 + 16);
      float4 fb = *(const float4*)(feats_in + ((size_t)z * N_ATOM + b) * 4);
      #pragma unroll
      for (int i = 0; i < 4; ++i) {
        float4 r0 = T0[i], r1 = T1[i];
        float v0 = r0.x + fr * (r1.x - r0.x);
        float v1 = r0.y + fr * (r1.y - r0.y);
        float v2 = r0.z + fr * (r1.z - r0.z);
        float v3 = r0.w + fr * (r1.w - r0.w);
        acc[i] += v0 * fb.x + v1 * fb.y + v2 * fb.z + v3 * fb.w;
      }
    }
  }
  #pragma unroll
  for (int m = 32; m > 0; m >>= 1) {
    #pragma unroll
    for (int i = 0; i < 4; ++i) acc[i] += __shfl_xor(acc[i], m, 64);
    cnt += __shfl_xor(cnt, m, 64);
  }
  if (lane == 0) {
    float nb = cnt < 1.0f ? 1.0f : cnt;
    float sc = 1.0f / sqrtf(nb);
    float4 o;
    o.x = acc[0] * sc; o.y = acc[1] * sc; o.z = acc[2] * sc; o.w = acc[3] * sc;
    *(float4*)(f_out + (size_t)row * 4) = o;
  }
}

// L2 pool over atoms -> FC(8->512)+softplus -> batchnorm over B -> softplus
// -> FC(512->1) -> sigmoid.   Single block of 512 threads.
__global__ __launch_bounds__(512) void tail_kernel(
    const float* __restrict__ f1, const float* __restrict__ f2,
    const float* __restrict__ fc_w, const float* __restrict__ fc_b,
    const float* __restrict__ bn_g, const float* __restrict__ bn_b,
    const float* __restrict__ out_w, const float* __restrict__ out_b,
    float* __restrict__ out) {
  __shared__ float pooled[16][8];
  __shared__ float part[8][16];
  const int tid = threadIdx.x;

  // pooling: 4 threads per (z,c) column, 4-lane shuffle reduce
  {
    int pair = tid >> 2;            // 0..127
    int sub  = tid & 3;
    int z = pair >> 3, c = pair & 7;
    const float* src = (c < 4) ? f1 : f2;
    int cc = c & 3;
    float s = 0.f;
    for (int a = sub; a < N_ATOM; a += 4) {
      float v = src[((size_t)z * N_ATOM + a) * 4 + cc];
      s += v * v;
    }
    s += __shfl_xor(s, 1, 64);
    s += __shfl_xor(s, 2, 64);
    if (sub == 0) pooled[z][c] = sqrtf(s);
  }
  __syncthreads();

  const int f = tid;
  float hv[16];
  float mean = 0.f;
  #pragma unroll
  for (int z = 0; z < 16; ++z) {
    float a = fc_b[f];
    #pragma unroll
    for (int c = 0; c < 8; ++c) a += pooled[z][c] * fc_w[c * FF_DIM + f];
    hv[z] = softplus_f(a);
    mean += hv[z];
  }
  mean *= (1.0f / 16.0f);
  float var = 0.f;
  #pragma unroll
  for (int z = 0; z < 16; ++z) { float d = hv[z] - mean; var += d * d; }
  var *= (1.0f / 16.0f);
  float istd = 1.0f / sqrtf(var + 1e-5f);
  float g = bn_g[f], bb = bn_b[f], ow = out_w[f];
  float contrib[16];
  #pragma unroll
  for (int z = 0; z < 16; ++z)
    contrib[z] = softplus_f((hv[z] - mean) * istd * g + bb) * ow;

  const int lane = tid & 63, wv = tid >> 6;
  #pragma unroll
  for (int m = 32; m > 0; m >>= 1) {
    #pragma unroll
    for (int z = 0; z < 16; ++z) contrib[z] += __shfl_xor(contrib[z], m, 64);
  }
  if (lane == 0) {
    #pragma unroll
    for (int z = 0; z < 16; ++z) part[wv][z] = contrib[z];
  }
  __syncthreads();
  if (tid < 16) {
    float s = out_b[0];
    #pragma unroll
    for (int w8 = 0; w8 < 8; ++w8) s += part[w8][tid];
    out[tid] = 1.0f / (1.0f + expf(-s));
  }
}

extern "C" void kernel_launch(void* const* d_in, const int* in_sizes, int n_in,
                              void* d_out, int out_size, void* d_ws, size_t ws_size,
                              hipStream_t stream) {
  const float* xyz = (const float*)d_in[0];
  const int*   Z   = (const int*)d_in[1];
  const float* emb = (const float*)d_in[2];
  const float* c0[8]; const float* c1[8];
  for (int i = 0; i < 8; ++i) {
    c0[i] = (const float*)d_in[3 + i];
    c1[i] = (const float*)d_in[11 + i];
  }
  const float* fc_w  = (const float*)d_in[19];
  const float* fc_b  = (const float*)d_in[20];
  const float* bn_g  = (const float*)d_in[21];
  const float* bn_b  = (const float*)d_in[22];
  const float* out_w = (const float*)d_in[23];
  const float* out_b = (const float*)d_in[24];
  float* out = (float*)d_out;

  float* wsf = (float*)d_ws;
  const size_t TAB_ELEMS = (size_t)NT * 16;
  float* t0 = wsf;
  float* t1 = t0 + TAB_ELEMS;
  float* feats0 = t1 + TAB_ELEMS;
  float* f1 = feats0 + (size_t)B_SZ * N_ATOM * 4;
  float* f2 = f1 + (size_t)B_SZ * N_ATOM * 4;

  gather_kernel<<<(B_SZ * N_ATOM + 255) / 256, 256, 0, stream>>>(Z, emb, feats0);

  table_kernel<<<2 * BLK_PER_CLOUD, 256, 0, stream>>>(
      c0[0], c0[1], c0[2], c0[3], c0[4], c0[5], c0[6], c0[7],
      c1[0], c1[1], c1[2], c1[3], c1[4], c1[5], c1[6], c1[7], t0, t1);

  const int conv_blocks = (B_SZ * N_ATOM) / 4;   // 1144, exact
  conv_kernel<<<conv_blocks, 256, 0, stream>>>(xyz, feats0, t0, f1);
  conv_kernel<<<conv_blocks, 256, 0, stream>>>(xyz, f1, t1, f2);

  tail_kernel<<<1, 512, 0, stream>>>(f1, f2, fc_w, fc_b, bn_g, bn_b,
                                     out_w, out_b, out);
}